// Round 5
// baseline (273.144 us; speedup 1.0000x reference)
//
#include <hip/hip_runtime.h>

#define BB 4
#define LL 1024
#define EE 1024
#define HH 16
#define HD 64
#define NBUCKET 33
#define SCALE 0.125f
#define SC2 (0.125f * 1.44269504088896f)

typedef unsigned short u16;
using f32x4 = __attribute__((ext_vector_type(4))) float;
using s16x8 = __attribute__((ext_vector_type(8))) short;

__device__ __forceinline__ u16 f2bf(float f) {
  union { float f; unsigned u; } x; x.f = f;
  unsigned r = (x.u + 0x7fffu + ((x.u >> 16) & 1u)) >> 16;
  return (u16)r;
}

__device__ __forceinline__ void gld_lds16(const void* g, void* s) {
  __builtin_amdgcn_global_load_lds((const __attribute__((address_space(1))) void*)g,
                                   (__attribute__((address_space(3))) void*)s, 16, 0, 0);
}

// ---------------- fp32 -> bf16 converts (single merged launch) ----------------
__global__ __launch_bounds__(256) void cvt_all(
    const float* __restrict__ q, const float* __restrict__ k, const float* __restrict__ v,
    const float* __restrict__ wq, const float* __restrict__ wk, const float* __restrict__ wv,
    const float* __restrict__ wo, const float* __restrict__ rk,
    u16* __restrict__ oq, u16* __restrict__ ok, u16* __restrict__ ov,
    u16* __restrict__ owq, u16* __restrict__ owk, u16* __restrict__ owv,
    u16* __restrict__ owo, u16* __restrict__ ork) {
  const int bid = blockIdx.x;
  const int tid = threadIdx.x;
  if (bid < 12288) {
    const int z = bid >> 12;
    const int i = (bid & 4095) * 256 + tid;
    const float* in = z == 0 ? q : (z == 1 ? k : v);
    u16* out = z == 0 ? oq : (z == 1 ? ok : ov);
    float4 f = ((const float4*)in)[i];
    ushort4 o;
    o.x = f2bf(f.x); o.y = f2bf(f.y); o.z = f2bf(f.z); o.w = f2bf(f.w);
    ((ushort4*)out)[i] = o;
  } else if (bid < 16384) {
    const int z = (bid - 12288) >> 10;
    const int i = ((bid - 12288) & 1023) * 256 + tid;
    const float* in = z == 0 ? wq : (z == 1 ? wk : (z == 2 ? wv : wo));
    u16* out = z == 0 ? owq : (z == 1 ? owk : (z == 2 ? owv : owo));
    float4 f = ((const float4*)in)[i];
    ushort4 o;
    o.x = f2bf(f.x); o.y = f2bf(f.y); o.z = f2bf(f.z); o.w = f2bf(f.w);
    ((ushort4*)out)[i] = o;
  } else {
    const int i = (bid - 16384) * 256 + tid;  // 12*256 = 3072 = 48*64 exact
    ork[i] = (i < 33 * 64) ? f2bf(rk[i]) : (u16)0;
  }
}

// ---------------- 128x128x64-tile bf16 GEMM, C = A * B^T + bias ----------------
template <int MODE>
__device__ __forceinline__ void gemm128_bt(const u16* __restrict__ A,
                                           const u16* __restrict__ Bw,
                                           const float* __restrict__ bias,
                                           u16* __restrict__ obf,
                                           float* __restrict__ ofp,
                                           int M, int N, int K, int m0, int n0) {
  __shared__ u16 a_sm[128 * 64];
  __shared__ u16 b_sm[128 * 64];
  const int tid = threadIdx.x;
  const int wave = tid >> 6, lane = tid & 63;
  const int row16 = lane & 15, quad = lane >> 4;
  const int wr = (wave >> 1) * 64, wc = (wave & 1) * 64;
  const int srow = lane >> 3, scol = (lane & 7) * 8;

  f32x4 acc[4][4] = {};

  for (int k0 = 0; k0 < K; k0 += 64) {
#pragma unroll
    for (int t = 0; t < 4; ++t) {
      const int chunk = wave * 4 + t;
      const int r = chunk * 8 + srow;
      gld_lds16(A + (size_t)(m0 + r) * K + k0 + scol, a_sm + chunk * 512);
      gld_lds16(Bw + (size_t)(n0 + r) * K + k0 + scol, b_sm + chunk * 512);
    }
    __syncthreads();
#pragma unroll
    for (int ks = 0; ks < 2; ++ks) {
      s16x8 af[4], bf[4];
#pragma unroll
      for (int mi = 0; mi < 4; ++mi)
        af[mi] = *(const s16x8*)&a_sm[(wr + mi * 16 + row16) * 64 + ks * 32 + quad * 8];
#pragma unroll
      for (int ni = 0; ni < 4; ++ni)
        bf[ni] = *(const s16x8*)&b_sm[(wc + ni * 16 + row16) * 64 + ks * 32 + quad * 8];
#pragma unroll
      for (int mi = 0; mi < 4; ++mi)
#pragma unroll
        for (int ni = 0; ni < 4; ++ni)
          acc[mi][ni] = __builtin_amdgcn_mfma_f32_16x16x32_bf16(af[mi], bf[ni], acc[mi][ni], 0, 0, 0);
    }
    __syncthreads();
  }

#pragma unroll
  for (int mi = 0; mi < 4; ++mi)
#pragma unroll
    for (int ni = 0; ni < 4; ++ni) {
      const int n = n0 + wc + ni * 16 + row16;
      const float bn = bias[n];
      if (MODE == 2) {
        const int mr0 = m0 + wr + mi * 16 + quad * 4;
        const int b = mr0 >> 10, l = mr0 & 1023;
        const int h = n >> 6, hd = n & 63;
        ushort4 o;
        o.x = f2bf(acc[mi][ni][0] + bn);
        o.y = f2bf(acc[mi][ni][1] + bn);
        o.z = f2bf(acc[mi][ni][2] + bn);
        o.w = f2bf(acc[mi][ni][3] + bn);
        *(ushort4*)&obf[((size_t)((b * HH + h) * HD + hd)) * LL + l] = o;
      } else {
#pragma unroll
        for (int r = 0; r < 4; ++r) {
          const int m = m0 + wr + mi * 16 + quad * 4 + r;
          const float v = acc[mi][ni][r] + bn;
          if (MODE == 0) {
            const int b = m >> 10, l = m & 1023, h = n >> 6, hd = n & 63;
            obf[((size_t)((b * HH + h) * LL + l)) * HD + hd] = f2bf(v);
          } else {
            ofp[(size_t)m * N + n] = v;
          }
        }
      }
    }
}

__global__ __launch_bounds__(256) void proj_gemm(
    const u16* __restrict__ xq, const u16* __restrict__ xk, const u16* __restrict__ xv,
    const u16* __restrict__ wqb, const u16* __restrict__ wkb, const u16* __restrict__ wvb,
    const float* __restrict__ bq, const float* __restrict__ bk, const float* __restrict__ bv,
    u16* __restrict__ oq, u16* __restrict__ ok, u16* __restrict__ ovt) {
  if (blockIdx.z == 0)
    gemm128_bt<0>(xq, wqb, bq, oq, nullptr, BB * LL, EE, EE, blockIdx.y * 128, blockIdx.x * 128);
  else if (blockIdx.z == 1)
    gemm128_bt<0>(xk, wkb, bk, ok, nullptr, BB * LL, EE, EE, blockIdx.y * 128, blockIdx.x * 128);
  else
    gemm128_bt<2>(xv, wvb, bv, ovt, nullptr, BB * LL, EE, EE, blockIdx.y * 128, blockIdx.x * 128);
}

__global__ __launch_bounds__(256) void out_gemm(const u16* __restrict__ Y,
                                                const u16* __restrict__ wob,
                                                const float* __restrict__ bo,
                                                float* __restrict__ out) {
  gemm128_bt<1>(Y, wob, bo, nullptr, out, BB * LL, EE, EE, blockIdx.y * 128, blockIdx.x * 128);
}

// ---------------- fused attention (round 5: 2 q-tiles/block + dbuf 1-barrier) ----
// grid 512 (= exactly 2 blocks/CU, no tail), block 256 (4 waves). Each block
// owns 128 q-rows of one bh; wave w owns q-tiles wq0a = i0+16w, wq0b = wq0a+64.
// Every staged K/V tile and every K/V ds_read fragment feeds BOTH q-tiles
// (2x MFMA per LDS/DMA byte). K/V double-buffered: stage jt+1 at iter top into
// alt buffer, single vmcnt+lgkm drain + barrier at iter END (DMA latency
// covered by the whole iteration's compute; buffer staged at jt was last read
// at jt-1, fenced by that iter's drain+barrier). One barrier per iter.
// LDS: kv 2x16K + qr 18432 + s 18432 = 69632 -> 2 blocks/CU exact.
__device__ __forceinline__ void softmax_pack(
    const f32x4 sacc[4], int j0, int wq0, float blo, float bhi,
    const float* qr_w, float* s_w, const int baseg[4], int row16,
    float& rsum, float& plos, float& phis, unsigned pk[4][2]) {
  const bool far_lo = (wq0 >= j0 + 79);
  const bool far_hi = (j0 >= wq0 + 31);
  if (far_lo || far_hi) {
    const float bb = (far_lo ? blo : bhi) * SC2;
    float tacc = 0.f;
#pragma unroll
    for (int g = 0; g < 4; ++g)
#pragma unroll
      for (int rr = 0; rr < 2; ++rr) {
        const float pv0 = __builtin_amdgcn_exp2f(sacc[g][rr * 2] * SC2 + bb);
        const float pv1 = __builtin_amdgcn_exp2f(sacc[g][rr * 2 + 1] * SC2 + bb);
        tacc += pv0 + pv1;
        unsigned c;
        asm("v_cvt_pk_bf16_f32 %0, %1, %2" : "=v"(c) : "v"(pv0), "v"(pv1));
        pk[g][rr] = c;
      }
    rsum += tacc;
    if (far_lo) plos += tacc; else phis += tacc;
  } else {
#pragma unroll
    for (int g = 0; g < 4; ++g)
#pragma unroll
      for (int rr = 0; rr < 2; ++rr) {
        float pv2[2];
#pragma unroll
        for (int e = 0; e < 2; ++e) {
          const int r = rr * 2 + e;
          const int dr = baseg[g] + j0 + r;
          int bk = dr < -16 ? -16 : (dr > 16 ? 16 : dr);
          bk += 16;
          const float bias = qr_w[bk * 17 + row16];
          const float pv = __builtin_amdgcn_exp2f((sacc[g][r] + bias) * SC2);
          pv2[e] = pv;
          rsum += pv;
          if (dr <= -16) plos += pv;
          else if (dr >= 16) phis += pv;
          else atomicAdd(&s_w[row16 * 36 + bk], pv);
        }
        unsigned c;
        asm("v_cvt_pk_bf16_f32 %0, %1, %2" : "=v"(c) : "v"(pv2[0]), "v"(pv2[1]));
        pk[g][rr] = c;
      }
  }
}

__device__ __forceinline__ void pf_assemble(const unsigned pk[4][2], s16x8 pf[2]) {
#pragma unroll
  for (int ks = 0; ks < 2; ++ks) {
    unsigned x0 = pk[ks * 2][0], y0 = pk[ks * 2 + 1][0];
    unsigned x1 = pk[ks * 2][1], y1 = pk[ks * 2 + 1][1];
    asm("v_permlane32_swap_b32 %0, %1" : "+v"(x0), "+v"(y0));
    asm("v_permlane32_swap_b32 %0, %1" : "+v"(x1), "+v"(y1));
    union { unsigned u[4]; s16x8 v; } pfu;
    pfu.u[0] = x0; pfu.u[1] = x1; pfu.u[2] = y0; pfu.u[3] = y1;
    pf[ks] = pfu.v;
  }
}

__global__ __launch_bounds__(256) void attn_fused(
    const u16* __restrict__ Q, const u16* __restrict__ Kb, const u16* __restrict__ Vt,
    const u16* __restrict__ RKp, const float* __restrict__ RV, u16* __restrict__ Y) {
  __shared__ __align__(16) float qr_sm[4][2][576];      // [wave][tile][bucket*17+q]
  __shared__ __align__(16) float s_sm[4][2][576];       // [wave][tile][q*36+bucket]
  __shared__ __align__(16) unsigned char kv[2][16384];  // dbuf K 8K | V 8K

  const int tid = threadIdx.x;
  const int wave = tid >> 6, lane = tid & 63;
  const int row16 = lane & 15, quad = lane >> 4;
  const int bh = blockIdx.x & 63;          // XCD swizzle: xcd = blk % 8 = bh % 8
  const int i0 = (blockIdx.x >> 6) * 128;
  const int wq0a = i0 + wave * 16;
  const int wq0b = wq0a + 64;
  const u16* qp = Q + (size_t)bh * LL * HD;
  const char* kpB = (const char*)(Kb + (size_t)bh * LL * HD);
  const char* vpB = (const char*)(Vt + (size_t)bh * HD * LL);

  float* qr_wa = &qr_sm[wave][0][0];
  float* qr_wb = &qr_sm[wave][1][0];
  float* s_wa = &s_sm[wave][0][0];
  float* s_wb = &s_sm[wave][1][0];

  // stage offsets (both-sides swizzle: linear LDS dest, pre-swizzled source)
  int srcK[2], srcV[2];
#pragma unroll
  for (int t = 0; t < 2; ++t) {
    const int cK = (wave * 2 + t) * 64 + lane;
    const int rw = cK >> 3;
    const int cb = ((cK * 16) & 127) ^ ((rw & 7) << 4);
    srcK[t] = rw * 128 + cb;
    srcV[t] = rw * 2048 + cb;
  }
  // rho' row permutation (swap 4-7 <-> 8-11 within each 16) for K reads
  const int q2 = row16 >> 2;
  const int prow = ((((q2 << 1) | (q2 >> 1)) & 3) << 2) + (row16 & 3);
  const int swzK = (prow & 7) << 4;
  const int swzV = (row16 & 7) << 4;
  const int rho4 = (((quad << 1) | (quad >> 1)) & 3) << 2;  // rho(quad)*4

  // ---- prologue: issue stage of tile 0 first, overlap with qr compute ----
#pragma unroll
  for (int t = 0; t < 2; ++t) {
    gld_lds16(kpB + srcK[t], kv[0] + (wave * 2 + t) * 1024);
    gld_lds16(vpB + srcV[t], kv[0] + 8192 + (wave * 2 + t) * 1024);
  }

  for (int t = lane; t < 1152; t += 64) s_wa[t] = 0.f;  // zeros both tiles (contig)

  // Q fragments (B-operand; identical lane layout to A for 16x16x32)
  s16x8 qfa[2], qfb[2];
#pragma unroll
  for (int ks = 0; ks < 2; ++ks) {
    qfa[ks] = *(const s16x8*)(qp + (size_t)(wq0a + row16) * HD + ks * 32 + quad * 8);
    qfb[ks] = *(const s16x8*)(qp + (size_t)(wq0b + row16) * HD + ks * 32 + quad * 8);
  }

  // qr^T[bucket][q] = rel_k[bucket] . q  via swapped MFMA (A=RK, B=Q); RK frag shared
  f32x4 a0a, a2a, a0b, a2b;
#pragma unroll
  for (int nt = 0; nt < 3; ++nt) {
    f32x4 aa = {}, ab = {};
#pragma unroll
    for (int ks = 0; ks < 2; ++ks) {
      s16x8 afr = *(const s16x8*)(RKp + (size_t)(nt * 16 + row16) * HD + ks * 32 + quad * 8);
      aa = __builtin_amdgcn_mfma_f32_16x16x32_bf16(afr, qfa[ks], aa, 0, 0, 0);
      ab = __builtin_amdgcn_mfma_f32_16x16x32_bf16(afr, qfb[ks], ab, 0, 0, 0);
    }
    if (nt == 0) { a0a = aa; a0b = ab; }
    if (nt == 2) { a2a = aa; a2b = ab; }
#pragma unroll
    for (int r = 0; r < 4; ++r) {
      const int bk = nt * 16 + quad * 4 + r;
      if (bk < NBUCKET) {
        qr_wa[bk * 17 + row16] = aa[r];
        qr_wb[bk * 17 + row16] = ab[r];
      }
    }
  }
  const float bloa = __shfl(a0a[0], row16);
  const float bhia = __shfl(a2a[0], row16);
  const float blob = __shfl(a0b[0], row16);
  const float bhib = __shfl(a2b[0], row16);

  f32x4 oa[4] = {}, ob[4] = {};
  float rsuma = 0.f, plosa = 0.f, phisa = 0.f;
  float rsumb = 0.f, plosb = 0.f, phisb = 0.f;
  int basega[4], basegb[4];
#pragma unroll
  for (int g = 0; g < 4; ++g) {
    basega[g] = g * 16 + rho4 - wq0a - row16;
    basegb[g] = basega[g] - 64;
  }

  // prologue drain: stage(0) + qf/qr loads complete, qr/s LDS writes done
  asm volatile("s_waitcnt vmcnt(0) lgkmcnt(0)" ::: "memory");
  __builtin_amdgcn_s_barrier();
  __builtin_amdgcn_sched_barrier(0);

  for (int jt = 0; jt < 16; ++jt) {
    const int j0 = jt * 64;
    const unsigned char* cur = kv[jt & 1];

    // ---- issue prefetch of tile jt+1 into alt buffer (drained at iter end) ----
    if (jt < 15) {
      unsigned char* nxt = (unsigned char*)kv[(jt + 1) & 1];
      const size_t j1 = (size_t)(j0 + 64);
#pragma unroll
      for (int t = 0; t < 2; ++t) {
        gld_lds16(kpB + j1 * 128 + srcK[t], nxt + (wave * 2 + t) * 1024);
        gld_lds16(vpB + j1 * 2 + srcV[t], nxt + 8192 + (wave * 2 + t) * 1024);
      }
    }

    // ---- S^T = K Q^T for both q-tiles; K fragment read ONCE, used twice ----
    f32x4 sa[4] = {}, sb[4] = {};
#pragma unroll
    for (int ks = 0; ks < 2; ++ks)
#pragma unroll
      for (int g = 0; g < 4; ++g) {
        const int L = (g * 16 + prow) * 128 + ks * 64 + quad * 16;
        const s16x8 kfr = *(const s16x8*)(cur + (L ^ swzK));
        sa[g] = __builtin_amdgcn_mfma_f32_16x16x32_bf16(kfr, qfa[ks], sa[g], 0, 0, 0);
        sb[g] = __builtin_amdgcn_mfma_f32_16x16x32_bf16(kfr, qfb[ks], sb[g], 0, 0, 0);
      }

    // ---- softmax + in-register bf16 pack, per tile ----
    unsigned pka[4][2], pkb[4][2];
    softmax_pack(sa, j0, wq0a, bloa, bhia, qr_wa, s_wa, basega, row16,
                 rsuma, plosa, phisa, pka);
    softmax_pack(sb, j0, wq0b, blob, bhib, qr_wb, s_wb, basegb, row16,
                 rsumb, plosb, phisb, pkb);

    s16x8 pfa[2], pfb[2];
    pf_assemble(pka, pfa);
    pf_assemble(pkb, pfb);

    // ---- O^T += V^T P^T ; V fragment read ONCE, used twice ----
#pragma unroll
    for (int ks = 0; ks < 2; ++ks)
#pragma unroll
      for (int dt = 0; dt < 4; ++dt) {
        const int L = (dt * 16 + row16) * 128 + ks * 64 + quad * 16;
        const s16x8 vfr = *(const s16x8*)(cur + 8192 + (L ^ swzV));
        oa[dt] = __builtin_amdgcn_mfma_f32_16x16x32_bf16(vfr, pfa[ks], oa[dt], 0, 0, 0);
        ob[dt] = __builtin_amdgcn_mfma_f32_16x16x32_bf16(vfr, pfb[ks], ob[dt], 0, 0, 0);
      }

    // end-of-iter: own LDS reads done (lgkm) + next tile's DMA landed (vmcnt),
    // then one barrier. Next iter's stage overwrites the buffer read THIS iter
    // -> fenced by this drain+barrier.
    asm volatile("s_waitcnt vmcnt(0) lgkmcnt(0)" ::: "memory");
    __builtin_amdgcn_s_barrier();
    __builtin_amdgcn_sched_barrier(0);
  }

  // quad-reduction of row sums (j space split across quads)
  float t1;
  t1 = rsuma + __shfl_xor(rsuma, 16); const float lacca = t1 + __shfl_xor(t1, 32);
  t1 = plosa + __shfl_xor(plosa, 16); const float sloa = t1 + __shfl_xor(t1, 32);
  t1 = phisa + __shfl_xor(phisa, 16); const float shia = t1 + __shfl_xor(t1, 32);
  t1 = rsumb + __shfl_xor(rsumb, 16); const float laccb = t1 + __shfl_xor(t1, 32);
  t1 = plosb + __shfl_xor(plosb, 16); const float slob = t1 + __shfl_xor(t1, 32);
  t1 = phisb + __shfl_xor(phisb, 16); const float shib = t1 + __shfl_xor(t1, 32);

  // epilogue: rel_v into kv (loop-final barrier fenced all reads)
  float* rv_sm = (float*)kv;
  for (int t = tid; t < NBUCKET * HD; t += 256) rv_sm[t] = RV[t];
  __syncthreads();

  const int b = bh >> 4, h = bh & 15;
#pragma unroll
  for (int tile = 0; tile < 2; ++tile) {
    const float* s_w = tile == 0 ? s_wa : s_wb;
    const float slo = tile == 0 ? sloa : slob;
    const float shi = tile == 0 ? shia : shib;
    const float lacc = tile == 0 ? lacca : laccb;
    const f32x4* oacc = tile == 0 ? oa : ob;
    const int wq0 = tile == 0 ? wq0a : wq0b;
    float rel[4][4] = {};
    for (int bk = 0; bk < NBUCKET; ++bk) {
      float sv = s_w[row16 * 36 + bk];
      if (bk == 0) sv += slo;
      if (bk == 32) sv += shi;
#pragma unroll
      for (int dt = 0; dt < 4; ++dt) {
        const f32x4 rv4 = *(const f32x4*)&rv_sm[bk * HD + dt * 16 + quad * 4];
#pragma unroll
        for (int r = 0; r < 4; ++r) rel[dt][r] += sv * rv4[r];
      }
    }
    const float inv = 1.0f / lacc;
#pragma unroll
    for (int dt = 0; dt < 4; ++dt) {
      ushort4 o;
      o.x = f2bf((oacc[dt][0] + rel[dt][0]) * inv);
      o.y = f2bf((oacc[dt][1] + rel[dt][1]) * inv);
      o.z = f2bf((oacc[dt][2] + rel[dt][2]) * inv);
      o.w = f2bf((oacc[dt][3] + rel[dt][3]) * inv);
      *(ushort4*)&Y[((size_t)(b * LL + wq0 + row16)) * EE + h * HD + dt * 16 + quad * 4] = o;
    }
  }
}

extern "C" void kernel_launch(void* const* d_in, const int* in_sizes, int n_in,
                              void* d_out, int out_size, void* d_ws, size_t ws_size,
                              hipStream_t stream) {
  const float* query = (const float*)d_in[0];
  const float* key_  = (const float*)d_in[1];
  const float* value = (const float*)d_in[2];
  const float* wq = (const float*)d_in[3];
  const float* bq = (const float*)d_in[4];
  const float* wk = (const float*)d_in[5];
  const float* bk = (const float*)d_in[6];
  const float* wv = (const float*)d_in[7];
  const float* bv = (const float*)d_in[8];
  const float* wo = (const float*)d_in[9];
  const float* bo = (const float*)d_in[10];
  const float* rel_k = (const float*)d_in[11];
  const float* rel_v = (const float*)d_in[12];

  char* base = (char*)d_ws;
  size_t off = 0;
  auto alloc = [&](size_t bytes) -> void* {
    void* p = base + off;
    off += (bytes + 255) & ~(size_t)255;
    return p;
  };
  const size_t XE = (size_t)BB * LL * EE;
  u16* xq    = (u16*)alloc(XE * 2);
  u16* xk    = (u16*)alloc(XE * 2);
  u16* xv    = (u16*)alloc(XE * 2);
  u16* wqb   = (u16*)alloc((size_t)EE * EE * 2);
  u16* wkb   = (u16*)alloc((size_t)EE * EE * 2);
  u16* wvb   = (u16*)alloc((size_t)EE * EE * 2);
  u16* wob   = (u16*)alloc((size_t)EE * EE * 2);
  u16* q_ws  = (u16*)alloc(XE * 2);
  u16* k_ws  = (u16*)alloc(XE * 2);
  u16* vt_ws = (u16*)alloc(XE * 2);
  u16* relkp = (u16*)alloc(48 * 64 * 2);
  u16* y_ws = xq;   // xq dead after proj_gemm (stream-ordered)

  cvt_all<<<16396, 256, 0, stream>>>(query, key_, value, wq, wk, wv, wo, rel_k,
                                     xq, xk, xv, wqb, wkb, wvb, wob, relkp);

  proj_gemm<<<dim3(EE / 128, BB * LL / 128, 3), 256, 0, stream>>>(
      xq, xk, xv, wqb, wkb, wvb, bq, bk, bv, q_ws, k_ws, vt_ws);

  attn_fused<<<512, 256, 0, stream>>>(q_ws, k_ws, vt_ws, relkp, rel_v, y_ws);

  out_gemm<<<dim3(EE / 128, BB * LL / 128), 256, 0, stream>>>(y_ws, wob, bo, (float*)d_out);
}

// Round 6
// 261.225 us; speedup vs baseline: 1.0456x; 1.0456x over previous
//
#include <hip/hip_runtime.h>

#define BB 4
#define LL 1024
#define EE 1024
#define HH 16
#define HD 64
#define NBUCKET 33
#define SCALE 0.125f
#define SC2 (0.125f * 1.44269504088896f)

typedef unsigned short u16;
using f32x4 = __attribute__((ext_vector_type(4))) float;
using s16x8 = __attribute__((ext_vector_type(8))) short;

__device__ __forceinline__ u16 f2bf(float f) {
  union { float f; unsigned u; } x; x.f = f;
  unsigned r = (x.u + 0x7fffu + ((x.u >> 16) & 1u)) >> 16;
  return (u16)r;
}

__device__ __forceinline__ void gld_lds16(const void* g, void* s) {
  __builtin_amdgcn_global_load_lds((const __attribute__((address_space(1))) void*)g,
                                   (__attribute__((address_space(3))) void*)s, 16, 0, 0);
}

// ---------------- weights + rel_k fp32->bf16 (inputs converted in proj_gemm) ----
__global__ __launch_bounds__(256) void cvt_w(
    const float* __restrict__ wq, const float* __restrict__ wk, const float* __restrict__ wv,
    const float* __restrict__ wo, const float* __restrict__ rk,
    u16* __restrict__ owq, u16* __restrict__ owk, u16* __restrict__ owv,
    u16* __restrict__ owo, u16* __restrict__ ork) {
  const int bid = blockIdx.x;
  const int tid = threadIdx.x;
  if (bid < 4096) {
    const int z = bid >> 10;
    const int i = (bid & 1023) * 256 + tid;
    const float* in = z == 0 ? wq : (z == 1 ? wk : (z == 2 ? wv : wo));
    u16* out = z == 0 ? owq : (z == 1 ? owk : (z == 2 ? owv : owo));
    float4 f = ((const float4*)in)[i];
    ushort4 o;
    o.x = f2bf(f.x); o.y = f2bf(f.y); o.z = f2bf(f.z); o.w = f2bf(f.w);
    ((ushort4*)out)[i] = o;
  } else {
    const int i = (bid - 4096) * 256 + tid;  // 12*256 = 3072 = 48*64 exact
    ork[i] = (i < 33 * 64) ? f2bf(rk[i]) : (u16)0;
  }
}

// ------- 128x128x64-tile GEMM, A fp32 (converted in-staging), B^T bf16 --------
// A-staging is reg-staged (global f32 -> v_cvt_pk_bf16_f32 -> ds_write_b128);
// B-staging keeps global_load_lds DMA. Layouts in LDS identical to the old
// all-bf16 path, so fragment reads/MFMA/epilogue are unchanged.
// MODE 0: store bf16 head-layout (B,H,L,HD).  MODE 2: bf16 (B,H,HD,L).
template <int MODE>
__device__ __forceinline__ void gemm128_f32a(const float* __restrict__ A,
                                             const u16* __restrict__ Bw,
                                             const float* __restrict__ bias,
                                             u16* __restrict__ obf,
                                             int M, int N, int K, int m0, int n0) {
  __shared__ u16 a_sm[128 * 64];
  __shared__ u16 b_sm[128 * 64];
  const int tid = threadIdx.x;
  const int wave = tid >> 6, lane = tid & 63;
  const int row16 = lane & 15, quad = lane >> 4;
  const int wr = (wave >> 1) * 64, wc = (wave & 1) * 64;
  const int srow = lane >> 3, scol = (lane & 7) * 8;

  f32x4 acc[4][4] = {};

  for (int k0 = 0; k0 < K; k0 += 64) {
    // B tile via DMA (16 chunks x 1KB)
#pragma unroll
    for (int t = 0; t < 4; ++t) {
      const int chunk = wave * 4 + t;
      const int r = chunk * 8 + srow;
      gld_lds16(Bw + (size_t)(n0 + r) * K + k0 + scol, b_sm + chunk * 512);
    }
    // A tile reg-staged: 1024 chunks of 32B f32; 4 per thread
#pragma unroll
    for (int p = 0; p < 4; ++p) {
      const int pc = p * 256 + tid;
      const int r = pc >> 3, c0 = (pc & 7) * 8;
      const float4* src = (const float4*)(A + (size_t)(m0 + r) * K + k0 + c0);
      const float4 f0 = src[0], f1 = src[1];
      unsigned w0, w1, w2, w3;
      asm("v_cvt_pk_bf16_f32 %0, %1, %2" : "=v"(w0) : "v"(f0.x), "v"(f0.y));
      asm("v_cvt_pk_bf16_f32 %0, %1, %2" : "=v"(w1) : "v"(f0.z), "v"(f0.w));
      asm("v_cvt_pk_bf16_f32 %0, %1, %2" : "=v"(w2) : "v"(f1.x), "v"(f1.y));
      asm("v_cvt_pk_bf16_f32 %0, %1, %2" : "=v"(w3) : "v"(f1.z), "v"(f1.w));
      union { unsigned u[4]; s16x8 v; } w;
      w.u[0] = w0; w.u[1] = w1; w.u[2] = w2; w.u[3] = w3;
      *(s16x8*)&a_sm[r * 64 + c0] = w.v;
    }
    __syncthreads();   // drains vmcnt (B DMA) + lgkm (A ds_writes)
#pragma unroll
    for (int ks = 0; ks < 2; ++ks) {
      s16x8 af[4], bf[4];
#pragma unroll
      for (int mi = 0; mi < 4; ++mi)
        af[mi] = *(const s16x8*)&a_sm[(wr + mi * 16 + row16) * 64 + ks * 32 + quad * 8];
#pragma unroll
      for (int ni = 0; ni < 4; ++ni)
        bf[ni] = *(const s16x8*)&b_sm[(wc + ni * 16 + row16) * 64 + ks * 32 + quad * 8];
#pragma unroll
      for (int mi = 0; mi < 4; ++mi)
#pragma unroll
        for (int ni = 0; ni < 4; ++ni)
          acc[mi][ni] = __builtin_amdgcn_mfma_f32_16x16x32_bf16(af[mi], bf[ni], acc[mi][ni], 0, 0, 0);
    }
    __syncthreads();
  }

#pragma unroll
  for (int mi = 0; mi < 4; ++mi)
#pragma unroll
    for (int ni = 0; ni < 4; ++ni) {
      const int n = n0 + wc + ni * 16 + row16;
      const float bn = bias[n];
      if (MODE == 2) {
        const int mr0 = m0 + wr + mi * 16 + quad * 4;
        const int b = mr0 >> 10, l = mr0 & 1023;
        const int h = n >> 6, hd = n & 63;
        ushort4 o;
        o.x = f2bf(acc[mi][ni][0] + bn);
        o.y = f2bf(acc[mi][ni][1] + bn);
        o.z = f2bf(acc[mi][ni][2] + bn);
        o.w = f2bf(acc[mi][ni][3] + bn);
        *(ushort4*)&obf[((size_t)((b * HH + h) * HD + hd)) * LL + l] = o;
      } else {
#pragma unroll
        for (int r = 0; r < 4; ++r) {
          const int m = m0 + wr + mi * 16 + quad * 4 + r;
          const float v = acc[mi][ni][r] + bn;
          const int b = m >> 10, l = m & 1023, h = n >> 6, hd = n & 63;
          obf[((size_t)((b * HH + h) * LL + l)) * HD + hd] = f2bf(v);
        }
      }
    }
}

// ---------------- all-bf16 128x128x64 GEMM (out projection) ----------------
__device__ __forceinline__ void gemm128_bt_f32out(const u16* __restrict__ A,
                                                  const u16* __restrict__ Bw,
                                                  const float* __restrict__ bias,
                                                  float* __restrict__ ofp,
                                                  int M, int N, int K, int m0, int n0) {
  __shared__ u16 a_sm[128 * 64];
  __shared__ u16 b_sm[128 * 64];
  const int tid = threadIdx.x;
  const int wave = tid >> 6, lane = tid & 63;
  const int row16 = lane & 15, quad = lane >> 4;
  const int wr = (wave >> 1) * 64, wc = (wave & 1) * 64;
  const int srow = lane >> 3, scol = (lane & 7) * 8;

  f32x4 acc[4][4] = {};

  for (int k0 = 0; k0 < K; k0 += 64) {
#pragma unroll
    for (int t = 0; t < 4; ++t) {
      const int chunk = wave * 4 + t;
      const int r = chunk * 8 + srow;
      gld_lds16(A + (size_t)(m0 + r) * K + k0 + scol, a_sm + chunk * 512);
      gld_lds16(Bw + (size_t)(n0 + r) * K + k0 + scol, b_sm + chunk * 512);
    }
    __syncthreads();
#pragma unroll
    for (int ks = 0; ks < 2; ++ks) {
      s16x8 af[4], bf[4];
#pragma unroll
      for (int mi = 0; mi < 4; ++mi)
        af[mi] = *(const s16x8*)&a_sm[(wr + mi * 16 + row16) * 64 + ks * 32 + quad * 8];
#pragma unroll
      for (int ni = 0; ni < 4; ++ni)
        bf[ni] = *(const s16x8*)&b_sm[(wc + ni * 16 + row16) * 64 + ks * 32 + quad * 8];
#pragma unroll
      for (int mi = 0; mi < 4; ++mi)
#pragma unroll
        for (int ni = 0; ni < 4; ++ni)
          acc[mi][ni] = __builtin_amdgcn_mfma_f32_16x16x32_bf16(af[mi], bf[ni], acc[mi][ni], 0, 0, 0);
    }
    __syncthreads();
  }

#pragma unroll
  for (int mi = 0; mi < 4; ++mi)
#pragma unroll
    for (int ni = 0; ni < 4; ++ni) {
      const int n = n0 + wc + ni * 16 + row16;
      const float bn = bias[n];
#pragma unroll
      for (int r = 0; r < 4; ++r) {
        const int m = m0 + wr + mi * 16 + quad * 4 + r;
        ofp[(size_t)m * N + n] = acc[mi][ni][r] + bn;
      }
    }
}

__global__ __launch_bounds__(256) void proj_gemm(
    const float* __restrict__ xq, const float* __restrict__ xk, const float* __restrict__ xv,
    const u16* __restrict__ wqb, const u16* __restrict__ wkb, const u16* __restrict__ wvb,
    const float* __restrict__ bq, const float* __restrict__ bk, const float* __restrict__ bv,
    u16* __restrict__ oq, u16* __restrict__ ok, u16* __restrict__ ovt) {
  if (blockIdx.z == 0)
    gemm128_f32a<0>(xq, wqb, bq, oq, BB * LL, EE, EE, blockIdx.y * 128, blockIdx.x * 128);
  else if (blockIdx.z == 1)
    gemm128_f32a<0>(xk, wkb, bk, ok, BB * LL, EE, EE, blockIdx.y * 128, blockIdx.x * 128);
  else  // V: store directly transposed (B,H,HD,L)
    gemm128_f32a<2>(xv, wvb, bv, ovt, BB * LL, EE, EE, blockIdx.y * 128, blockIdx.x * 128);
}

__global__ __launch_bounds__(256) void out_gemm(const u16* __restrict__ Y,
                                                const u16* __restrict__ wob,
                                                const float* __restrict__ bo,
                                                float* __restrict__ out) {
  gemm128_bt_f32out(Y, wob, bo, out, BB * LL, EE, EE, blockIdx.y * 128, blockIdx.x * 128);
}

// ---------------- fused attention (round-4-proven, verbatim) ----------------
// grid 1024, block 256 (4 waves). Swapped-operand MFMA: QK -> mfma(K,Q), lane
// holds S^T for ONE q-row; P assembled IN REGISTERS (8 cvt_pk + 4 permlane32).
// LDS: kv 16384 (K 8K | V 8K) + qr 9216 + s 9216 = 34816 -> 4 blocks/CU.
// VGPR 80. NOTE round-5 evidence: 2-q-tile merge -> VGPR 156, occupancy
// halved, 61->82 us. Do NOT add per-iteration register state here.
__global__ __launch_bounds__(256) void attn_fused(
    const u16* __restrict__ Q, const u16* __restrict__ Kb, const u16* __restrict__ Vt,
    const u16* __restrict__ RKp, const float* __restrict__ RV, u16* __restrict__ Y) {
  __shared__ __align__(16) float qr_sm[4][576];     // [bucket][q] stride 17
  __shared__ __align__(16) float s_sm[4][16 * 36];  // [q][bucket] stride 36
  __shared__ __align__(16) unsigned char kv[16384]; // K 8K | V 8K; rv_sm epilogue

  const int tid = threadIdx.x;
  const int wave = tid >> 6, lane = tid & 63;
  const int row16 = lane & 15, quad = lane >> 4;
  const int bh = blockIdx.x & 63;          // XCD swizzle
  const int i0 = (blockIdx.x >> 6) * 64;
  const int wq0 = i0 + wave * 16;
  const u16* qp = Q + (size_t)bh * LL * HD;
  const char* kpB = (const char*)(Kb + (size_t)bh * LL * HD);
  const char* vpB = (const char*)(Vt + (size_t)bh * HD * LL);

  float* qr_w = &qr_sm[wave][0];
  float* s_w = &s_sm[wave][0];

  // stage offsets (both-sides swizzle: linear LDS dest, pre-swizzled source)
  int srcK[2], srcV[2];
#pragma unroll
  for (int t = 0; t < 2; ++t) {
    const int cK = (wave * 2 + t) * 64 + lane;
    const int rw = cK >> 3;
    const int cb = ((cK * 16) & 127) ^ ((rw & 7) << 4);
    srcK[t] = rw * 128 + cb;
    srcV[t] = rw * 2048 + cb;
  }
  // rho' row permutation (swap 4-7 <-> 8-11 within each 16) for K reads
  const int q2 = row16 >> 2;
  const int prow = ((((q2 << 1) | (q2 >> 1)) & 3) << 2) + (row16 & 3);
  const int swzK = (prow & 7) << 4;
  const int swzV = (row16 & 7) << 4;
  const int rho4 = (((quad << 1) | (quad >> 1)) & 3) << 2;  // rho(quad)*4

  // ---- prologue: issue stage of tile 0 first, overlap with qr compute ----
#pragma unroll
  for (int t = 0; t < 2; ++t) {
    gld_lds16(kpB + srcK[t], kv + (wave * 2 + t) * 1024);
    gld_lds16(vpB + srcV[t], kv + 8192 + (wave * 2 + t) * 1024);
  }

  for (int t = lane; t < 16 * 36; t += 64) s_w[t] = 0.f;

  // Q fragments (B-operand; identical lane layout to A for 16x16x32)
  s16x8 qf[2];
#pragma unroll
  for (int ks = 0; ks < 2; ++ks)
    qf[ks] = *(const s16x8*)(qp + (size_t)(wq0 + row16) * HD + ks * 32 + quad * 8);

  // qr^T[bucket][q] = rel_k[bucket] . q  via swapped MFMA (A=RK, B=Q)
  f32x4 a0, a2;
#pragma unroll
  for (int nt = 0; nt < 3; ++nt) {
    f32x4 a = {};
#pragma unroll
    for (int ks = 0; ks < 2; ++ks) {
      s16x8 afr = *(const s16x8*)(RKp + (size_t)(nt * 16 + row16) * HD + ks * 32 + quad * 8);
      a = __builtin_amdgcn_mfma_f32_16x16x32_bf16(afr, qf[ks], a, 0, 0, 0);
    }
    if (nt == 0) a0 = a;
    if (nt == 2) a2 = a;
#pragma unroll
    for (int r = 0; r < 4; ++r) {
      const int bk = nt * 16 + quad * 4 + r;
      if (bk < NBUCKET) qr_w[bk * 17 + row16] = a[r];
    }
  }
  // far biases: bucket 0 / 32 value for this lane's q-row (= row16)
  const float blo = __shfl(a0[0], row16);
  const float bhi = __shfl(a2[0], row16);

  f32x4 oacc[4] = {};
  float rsum = 0.f, plos = 0.f, phis = 0.f;
  int baseg[4];
#pragma unroll
  for (int g = 0; g < 4; ++g) baseg[g] = g * 16 + rho4 - wq0 - row16;

  for (int jt = 0; jt < 16; ++jt) {
    const int j0 = jt * 64;
    if (jt) {  // re-stage K/V tile (single buffer; end-of-iter barrier fenced reads)
#pragma unroll
      for (int t = 0; t < 2; ++t) {
        gld_lds16(kpB + (size_t)j0 * 128 + srcK[t], kv + (wave * 2 + t) * 1024);
        gld_lds16(vpB + (size_t)j0 * 2 + srcV[t], kv + 8192 + (wave * 2 + t) * 1024);
      }
    }
    asm volatile("s_waitcnt vmcnt(0)" ::: "memory");
    __builtin_amdgcn_s_barrier();
    __builtin_amdgcn_sched_barrier(0);

    // ---- S^T = K Q^T : lane holds S^T[j = j0+g*16+rho4+r][q = wq0+row16] ----
    f32x4 sacc[4] = {};
#pragma unroll
    for (int ks = 0; ks < 2; ++ks)
#pragma unroll
      for (int g = 0; g < 4; ++g) {
        const int L = (g * 16 + prow) * 128 + ks * 64 + quad * 16;
        const s16x8 kfr = *(const s16x8*)(kv + (L ^ swzK));
        sacc[g] = __builtin_amdgcn_mfma_f32_16x16x32_bf16(kfr, qf[ks], sacc[g], 0, 0, 0);
      }

    // ---- softmax + bf16 pack (all in registers) ----
    unsigned pk[4][2];
    const bool far_lo = (wq0 >= j0 + 79);
    const bool far_hi = (j0 >= wq0 + 31);
    if (far_lo || far_hi) {
      const float bb = (far_lo ? blo : bhi) * SC2;
      float tacc = 0.f;
#pragma unroll
      for (int g = 0; g < 4; ++g)
#pragma unroll
        for (int rr = 0; rr < 2; ++rr) {
          const float pv0 = __builtin_amdgcn_exp2f(sacc[g][rr * 2] * SC2 + bb);
          const float pv1 = __builtin_amdgcn_exp2f(sacc[g][rr * 2 + 1] * SC2 + bb);
          tacc += pv0 + pv1;
          unsigned c;
          asm("v_cvt_pk_bf16_f32 %0, %1, %2" : "=v"(c) : "v"(pv0), "v"(pv1));
          pk[g][rr] = c;
        }
      rsum += tacc;
      if (far_lo) plos += tacc; else phis += tacc;
    } else {
#pragma unroll
      for (int g = 0; g < 4; ++g)
#pragma unroll
        for (int rr = 0; rr < 2; ++rr) {
          float pv2[2];
#pragma unroll
          for (int e = 0; e < 2; ++e) {
            const int r = rr * 2 + e;
            const int dr = baseg[g] + j0 + r;
            int bk = dr < -16 ? -16 : (dr > 16 ? 16 : dr);
            bk += 16;
            const float bias = qr_w[bk * 17 + row16];
            const float pv = __builtin_amdgcn_exp2f((sacc[g][r] + bias) * SC2);
            pv2[e] = pv;
            rsum += pv;
            if (dr <= -16) plos += pv;
            else if (dr >= 16) phis += pv;
            else atomicAdd(&s_w[row16 * 36 + bk], pv);
          }
          unsigned c;
          asm("v_cvt_pk_bf16_f32 %0, %1, %2" : "=v"(c) : "v"(pv2[0]), "v"(pv2[1]));
          pk[g][rr] = c;
        }
    }

    // ---- P^T B-frag assembly: 4 permlane32_swap, zero LDS ----
    s16x8 pf[2];
#pragma unroll
    for (int ks = 0; ks < 2; ++ks) {
      unsigned x0 = pk[ks * 2][0], y0 = pk[ks * 2 + 1][0];
      unsigned x1 = pk[ks * 2][1], y1 = pk[ks * 2 + 1][1];
      asm("v_permlane32_swap_b32 %0, %1" : "+v"(x0), "+v"(y0));
      asm("v_permlane32_swap_b32 %0, %1" : "+v"(x1), "+v"(y1));
      union { unsigned u[4]; s16x8 v; } pfu;
      pfu.u[0] = x0; pfu.u[1] = x1; pfu.u[2] = y0; pfu.u[3] = y1;
      pf[ks] = pfu.v;
    }

    // ---- O^T += V^T P^T ----
#pragma unroll
    for (int ks = 0; ks < 2; ++ks)
#pragma unroll
      for (int dt = 0; dt < 4; ++dt) {
        const int L = (dt * 16 + row16) * 128 + ks * 64 + quad * 16;
        const s16x8 vfr = *(const s16x8*)(kv + 8192 + (L ^ swzV));
        oacc[dt] = __builtin_amdgcn_mfma_f32_16x16x32_bf16(vfr, pf[ks], oacc[dt], 0, 0, 0);
      }

    asm volatile("s_waitcnt lgkmcnt(0)" ::: "memory");
    __builtin_amdgcn_s_barrier();
    __builtin_amdgcn_sched_barrier(0);
  }

  // quad-reduction of row sums (j space was split across quads)
  float t1 = rsum + __shfl_xor(rsum, 16);
  const float lacc = t1 + __shfl_xor(t1, 32);
  t1 = plos + __shfl_xor(plos, 16);
  const float slo = t1 + __shfl_xor(t1, 32);
  t1 = phis + __shfl_xor(phis, 16);
  const float shi = t1 + __shfl_xor(t1, 32);

  // epilogue: rel_v into kv (loop-final barrier fenced all reads)
  float* rv_sm = (float*)kv;
  for (int t = tid; t < NBUCKET * HD; t += 256) rv_sm[t] = RV[t];
  __syncthreads();

  const int b = bh >> 4, h = bh & 15;
  float rel[4][4] = {};
  for (int bk = 0; bk < NBUCKET; ++bk) {
    float sv = s_w[row16 * 36 + bk];
    if (bk == 0) sv += slo;
    if (bk == 32) sv += shi;
#pragma unroll
    for (int dt = 0; dt < 4; ++dt) {
      const f32x4 rv4 = *(const f32x4*)&rv_sm[bk * HD + dt * 16 + quad * 4];
#pragma unroll
      for (int r = 0; r < 4; ++r) rel[dt][r] += sv * rv4[r];
    }
  }
  const float inv = 1.0f / lacc;
#pragma unroll
  for (int dt = 0; dt < 4; ++dt) {
    ushort4 o;
    o.x = f2bf((oacc[dt][0] + rel[dt][0]) * inv);
    o.y = f2bf((oacc[dt][1] + rel[dt][1]) * inv);
    o.z = f2bf((oacc[dt][2] + rel[dt][2]) * inv);
    o.w = f2bf((oacc[dt][3] + rel[dt][3]) * inv);
    *(ushort4*)&Y[((size_t)(b * LL + wq0 + row16)) * EE + h * HD + dt * 16 + quad * 4] = o;
  }
}

extern "C" void kernel_launch(void* const* d_in, const int* in_sizes, int n_in,
                              void* d_out, int out_size, void* d_ws, size_t ws_size,
                              hipStream_t stream) {
  const float* query = (const float*)d_in[0];
  const float* key_  = (const float*)d_in[1];
  const float* value = (const float*)d_in[2];
  const float* wq = (const float*)d_in[3];
  const float* bq = (const float*)d_in[4];
  const float* wk = (const float*)d_in[5];
  const float* bk = (const float*)d_in[6];
  const float* wv = (const float*)d_in[7];
  const float* bv = (const float*)d_in[8];
  const float* wo = (const float*)d_in[9];
  const float* bo = (const float*)d_in[10];
  const float* rel_k = (const float*)d_in[11];
  const float* rel_v = (const float*)d_in[12];

  char* base = (char*)d_ws;
  size_t off = 0;
  auto alloc = [&](size_t bytes) -> void* {
    void* p = base + off;
    off += (bytes + 255) & ~(size_t)255;
    return p;
  };
  const size_t XE = (size_t)BB * LL * EE;
  u16* wqb   = (u16*)alloc((size_t)EE * EE * 2);
  u16* wkb   = (u16*)alloc((size_t)EE * EE * 2);
  u16* wvb   = (u16*)alloc((size_t)EE * EE * 2);
  u16* wob   = (u16*)alloc((size_t)EE * EE * 2);
  u16* q_ws  = (u16*)alloc(XE * 2);
  u16* k_ws  = (u16*)alloc(XE * 2);
  u16* vt_ws = (u16*)alloc(XE * 2);   // V stored transposed by proj_gemm
  u16* relkp = (u16*)alloc(48 * 64 * 2);
  u16* y_ws  = (u16*)alloc(XE * 2);

  cvt_w<<<4108, 256, 0, stream>>>(wq, wk, wv, wo, rel_k, wqb, wkb, wvb, wob, relkp);

  proj_gemm<<<dim3(EE / 128, BB * LL / 128, 3), 256, 0, stream>>>(
      query, key_, value, wqb, wkb, wvb, bq, bk, bv, q_ws, k_ws, vt_ws);

  attn_fused<<<1024, 256, 0, stream>>>(q_ws, k_ws, vt_ws, relkp, rel_v, y_ws);

  out_gemm<<<dim3(EE / 128, BB * LL / 128), 256, 0, stream>>>(y_ws, wob, bo, (float*)d_out);
}

// Round 7
// 251.239 us; speedup vs baseline: 1.0872x; 1.0397x over previous
//
#include <hip/hip_runtime.h>

#define BB 4
#define LL 1024
#define EE 1024
#define HH 16
#define HD 64
#define NBUCKET 33
#define SCALE 0.125f
#define SC2 (0.125f * 1.44269504088896f)

typedef unsigned short u16;
using f32x4 = __attribute__((ext_vector_type(4))) float;
using s16x8 = __attribute__((ext_vector_type(8))) short;

__device__ __forceinline__ u16 f2bf(float f) {
  union { float f; unsigned u; } x; x.f = f;
  unsigned r = (x.u + 0x7fffu + ((x.u >> 16) & 1u)) >> 16;
  return (u16)r;
}

__device__ __forceinline__ void gld_lds16(const void* g, void* s) {
  __builtin_amdgcn_global_load_lds((const __attribute__((address_space(1))) void*)g,
                                   (__attribute__((address_space(3))) void*)s, 16, 0, 0);
}

// ---------------- weights + rel_k fp32->bf16 (inputs converted in proj_gemm) ----
__global__ __launch_bounds__(256) void cvt_w(
    const float* __restrict__ wq, const float* __restrict__ wk, const float* __restrict__ wv,
    const float* __restrict__ wo, const float* __restrict__ rk,
    u16* __restrict__ owq, u16* __restrict__ owk, u16* __restrict__ owv,
    u16* __restrict__ owo, u16* __restrict__ ork) {
  const int bid = blockIdx.x;
  const int tid = threadIdx.x;
  if (bid < 4096) {
    const int z = bid >> 10;
    const int i = (bid & 1023) * 256 + tid;
    const float* in = z == 0 ? wq : (z == 1 ? wk : (z == 2 ? wv : wo));
    u16* out = z == 0 ? owq : (z == 1 ? owk : (z == 2 ? owv : owo));
    float4 f = ((const float4*)in)[i];
    ushort4 o;
    o.x = f2bf(f.x); o.y = f2bf(f.y); o.z = f2bf(f.z); o.w = f2bf(f.w);
    ((ushort4*)out)[i] = o;
  } else {
    const int i = (bid - 4096) * 256 + tid;  // 12*256 = 3072 = 48*64 exact
    ork[i] = (i < 33 * 64) ? f2bf(rk[i]) : (u16)0;
  }
}

// ------- 128x128x64-tile GEMM, A fp32 (converted in-staging), B^T bf16 --------
// Round-7 fixes (from round-6 proj counters: FETCH 200MB, 9.4M bank-conflict
// cycles, LDS 64KB):
//  * shared tiles hoisted to kernel scope (one 32KB set, not per-instantiation)
//  * T2 both-sides XOR swizzle: B DMA source pre-swizzled (col16B ^= (row&7)),
//    A reg-stage ds_write to swizzled addr; ALL frag reads XOR by (row16&7)*8.
//    Kills the 16-way ds_read_b128 same-bank conflict of the 128B-stride tile.
//  * callers use a 1D grid with XCD-chunk remap so the 8 n0-blocks sharing an
//    A-panel land on ONE XCD's L2 (was: consecutive ids -> 8 different XCDs).
template <int MODE>
__device__ __forceinline__ void gemm128_f32a(u16* a_sm, u16* b_sm,
                                             const float* __restrict__ A,
                                             const u16* __restrict__ Bw,
                                             const float* __restrict__ bias,
                                             u16* __restrict__ obf,
                                             int M, int N, int K, int m0, int n0) {
  const int tid = threadIdx.x;
  const int wave = tid >> 6, lane = tid & 63;
  const int row16 = lane & 15, quad = lane >> 4;
  const int wr = (wave >> 1) * 64, wc = (wave & 1) * 64;
  const int srow = lane >> 3, scol = (lane & 7) * 8;
  const int rsw = (row16 & 7) * 8;  // frag-read XOR (u16 units)

  f32x4 acc[4][4] = {};

  for (int k0 = 0; k0 < K; k0 += 64) {
    // B tile via DMA, source pre-swizzled (linear LDS dest — rule 21)
#pragma unroll
    for (int t = 0; t < 4; ++t) {
      const int chunk = wave * 4 + t;
      const int r = chunk * 8 + srow;
      const int cs = scol ^ ((r & 7) * 8);
      gld_lds16(Bw + (size_t)(n0 + r) * K + k0 + cs, b_sm + chunk * 512);
    }
    // A tile reg-staged f32 -> bf16, ds_write to swizzled address
#pragma unroll
    for (int p = 0; p < 4; ++p) {
      const int pc = p * 256 + tid;
      const int r = pc >> 3, c0 = (pc & 7) * 8;
      const float4* src = (const float4*)(A + (size_t)(m0 + r) * K + k0 + c0);
      const float4 f0 = src[0], f1 = src[1];
      unsigned w0, w1, w2, w3;
      asm("v_cvt_pk_bf16_f32 %0, %1, %2" : "=v"(w0) : "v"(f0.x), "v"(f0.y));
      asm("v_cvt_pk_bf16_f32 %0, %1, %2" : "=v"(w1) : "v"(f0.z), "v"(f0.w));
      asm("v_cvt_pk_bf16_f32 %0, %1, %2" : "=v"(w2) : "v"(f1.x), "v"(f1.y));
      asm("v_cvt_pk_bf16_f32 %0, %1, %2" : "=v"(w3) : "v"(f1.z), "v"(f1.w));
      union { unsigned u[4]; s16x8 v; } w;
      w.u[0] = w0; w.u[1] = w1; w.u[2] = w2; w.u[3] = w3;
      *(s16x8*)&a_sm[r * 64 + (c0 ^ ((r & 7) * 8))] = w.v;
    }
    __syncthreads();   // drains vmcnt (B DMA) + lgkm (A ds_writes)
#pragma unroll
    for (int ks = 0; ks < 2; ++ks) {
      const int cfs = (ks * 32 + quad * 8) ^ rsw;
      s16x8 af[4], bf[4];
#pragma unroll
      for (int mi = 0; mi < 4; ++mi)
        af[mi] = *(const s16x8*)&a_sm[(wr + mi * 16 + row16) * 64 + cfs];
#pragma unroll
      for (int ni = 0; ni < 4; ++ni)
        bf[ni] = *(const s16x8*)&b_sm[(wc + ni * 16 + row16) * 64 + cfs];
#pragma unroll
      for (int mi = 0; mi < 4; ++mi)
#pragma unroll
        for (int ni = 0; ni < 4; ++ni)
          acc[mi][ni] = __builtin_amdgcn_mfma_f32_16x16x32_bf16(af[mi], bf[ni], acc[mi][ni], 0, 0, 0);
    }
    __syncthreads();
  }

#pragma unroll
  for (int mi = 0; mi < 4; ++mi)
#pragma unroll
    for (int ni = 0; ni < 4; ++ni) {
      const int n = n0 + wc + ni * 16 + row16;
      const float bn = bias[n];
      if (MODE == 2) {
        const int mr0 = m0 + wr + mi * 16 + quad * 4;
        const int b = mr0 >> 10, l = mr0 & 1023;
        const int h = n >> 6, hd = n & 63;
        ushort4 o;
        o.x = f2bf(acc[mi][ni][0] + bn);
        o.y = f2bf(acc[mi][ni][1] + bn);
        o.z = f2bf(acc[mi][ni][2] + bn);
        o.w = f2bf(acc[mi][ni][3] + bn);
        *(ushort4*)&obf[((size_t)((b * HH + h) * HD + hd)) * LL + l] = o;
      } else {
#pragma unroll
        for (int r = 0; r < 4; ++r) {
          const int m = m0 + wr + mi * 16 + quad * 4 + r;
          const float v = acc[mi][ni][r] + bn;
          const int b = m >> 10, l = m & 1023, h = n >> 6, hd = n & 63;
          obf[((size_t)((b * HH + h) * LL + l)) * HD + hd] = f2bf(v);
        }
      }
    }
}

__global__ __launch_bounds__(256) void proj_gemm(
    const float* __restrict__ xq, const float* __restrict__ xk, const float* __restrict__ xv,
    const u16* __restrict__ wqb, const u16* __restrict__ wkb, const u16* __restrict__ wvb,
    const float* __restrict__ bq, const float* __restrict__ bk, const float* __restrict__ bv,
    u16* __restrict__ oq, u16* __restrict__ ok, u16* __restrict__ ovt) {
  __shared__ u16 a_sm[128 * 64];
  __shared__ u16 b_sm[128 * 64];
  // XCD-chunk remap (nwg=768, 768%8==0 -> bijective): blocks sharing an
  // A-panel (n0 fastest) are contiguous within one XCD's chunk of 96.
  const int work = (blockIdx.x & 7) * 96 + (blockIdx.x >> 3);
  const int z = work >> 8;
  const int m0 = ((work & 255) >> 3) * 128;
  const int n0 = (work & 7) * 128;
  if (z == 0)
    gemm128_f32a<0>(a_sm, b_sm, xq, wqb, bq, oq, BB * LL, EE, EE, m0, n0);
  else if (z == 1)
    gemm128_f32a<0>(a_sm, b_sm, xk, wkb, bk, ok, BB * LL, EE, EE, m0, n0);
  else  // V: store directly transposed (B,H,HD,L)
    gemm128_f32a<2>(a_sm, b_sm, xv, wvb, bv, ovt, BB * LL, EE, EE, m0, n0);
}

// ---------------- all-bf16 128x128x64 GEMM (out projection) ----------------
__global__ __launch_bounds__(256) void out_gemm(const u16* __restrict__ A,
                                                const u16* __restrict__ Bw,
                                                const float* __restrict__ bias,
                                                float* __restrict__ ofp) {
  __shared__ u16 a_sm[128 * 64];
  __shared__ u16 b_sm[128 * 64];
  const int work = (blockIdx.x & 7) * 32 + (blockIdx.x >> 3);  // nwg=256, 256%8==0
  const int m0 = (work >> 3) * 128;
  const int n0 = (work & 7) * 128;
  const int N = EE, K = EE;

  const int tid = threadIdx.x;
  const int wave = tid >> 6, lane = tid & 63;
  const int row16 = lane & 15, quad = lane >> 4;
  const int wr = (wave >> 1) * 64, wc = (wave & 1) * 64;
  const int srow = lane >> 3, scol = (lane & 7) * 8;
  const int rsw = (row16 & 7) * 8;

  f32x4 acc[4][4] = {};

  for (int k0 = 0; k0 < K; k0 += 64) {
#pragma unroll
    for (int t = 0; t < 4; ++t) {
      const int chunk = wave * 4 + t;
      const int r = chunk * 8 + srow;
      const int cs = scol ^ ((r & 7) * 8);
      gld_lds16(A + (size_t)(m0 + r) * K + k0 + cs, a_sm + chunk * 512);
      gld_lds16(Bw + (size_t)(n0 + r) * K + k0 + cs, b_sm + chunk * 512);
    }
    __syncthreads();
#pragma unroll
    for (int ks = 0; ks < 2; ++ks) {
      const int cfs = (ks * 32 + quad * 8) ^ rsw;
      s16x8 af[4], bf[4];
#pragma unroll
      for (int mi = 0; mi < 4; ++mi)
        af[mi] = *(const s16x8*)&a_sm[(wr + mi * 16 + row16) * 64 + cfs];
#pragma unroll
      for (int ni = 0; ni < 4; ++ni)
        bf[ni] = *(const s16x8*)&b_sm[(wc + ni * 16 + row16) * 64 + cfs];
#pragma unroll
      for (int mi = 0; mi < 4; ++mi)
#pragma unroll
        for (int ni = 0; ni < 4; ++ni)
          acc[mi][ni] = __builtin_amdgcn_mfma_f32_16x16x32_bf16(af[mi], bf[ni], acc[mi][ni], 0, 0, 0);
    }
    __syncthreads();
  }

#pragma unroll
  for (int mi = 0; mi < 4; ++mi)
#pragma unroll
    for (int ni = 0; ni < 4; ++ni) {
      const int n = n0 + wc + ni * 16 + row16;
      const float bn = bias[n];
#pragma unroll
      for (int r = 0; r < 4; ++r) {
        const int m = m0 + wr + mi * 16 + quad * 4 + r;
        ofp[(size_t)m * N + n] = acc[mi][ni][r] + bn;
      }
    }
}

// ---------------- fused attention (round-4-proven, verbatim) ----------------
// grid 1024, block 256 (4 waves). Swapped-operand MFMA: QK -> mfma(K,Q), lane
// holds S^T for ONE q-row; P assembled IN REGISTERS (8 cvt_pk + 4 permlane32).
// LDS: kv 16384 (K 8K | V 8K) + qr 9216 + s 9216 = 34816 -> 4 blocks/CU.
// VGPR 80. NOTE round-5 evidence: 2-q-tile merge -> VGPR 156, occupancy
// halved, 61->82 us. Do NOT add per-iteration register state here.
__global__ __launch_bounds__(256) void attn_fused(
    const u16* __restrict__ Q, const u16* __restrict__ Kb, const u16* __restrict__ Vt,
    const u16* __restrict__ RKp, const float* __restrict__ RV, u16* __restrict__ Y) {
  __shared__ __align__(16) float qr_sm[4][576];     // [bucket][q] stride 17
  __shared__ __align__(16) float s_sm[4][16 * 36];  // [q][bucket] stride 36
  __shared__ __align__(16) unsigned char kv[16384]; // K 8K | V 8K; rv_sm epilogue

  const int tid = threadIdx.x;
  const int wave = tid >> 6, lane = tid & 63;
  const int row16 = lane & 15, quad = lane >> 4;
  const int bh = blockIdx.x & 63;          // XCD swizzle
  const int i0 = (blockIdx.x >> 6) * 64;
  const int wq0 = i0 + wave * 16;
  const u16* qp = Q + (size_t)bh * LL * HD;
  const char* kpB = (const char*)(Kb + (size_t)bh * LL * HD);
  const char* vpB = (const char*)(Vt + (size_t)bh * HD * LL);

  float* qr_w = &qr_sm[wave][0];
  float* s_w = &s_sm[wave][0];

  // stage offsets (both-sides swizzle: linear LDS dest, pre-swizzled source)
  int srcK[2], srcV[2];
#pragma unroll
  for (int t = 0; t < 2; ++t) {
    const int cK = (wave * 2 + t) * 64 + lane;
    const int rw = cK >> 3;
    const int cb = ((cK * 16) & 127) ^ ((rw & 7) << 4);
    srcK[t] = rw * 128 + cb;
    srcV[t] = rw * 2048 + cb;
  }
  // rho' row permutation (swap 4-7 <-> 8-11 within each 16) for K reads
  const int q2 = row16 >> 2;
  const int prow = ((((q2 << 1) | (q2 >> 1)) & 3) << 2) + (row16 & 3);
  const int swzK = (prow & 7) << 4;
  const int swzV = (row16 & 7) << 4;
  const int rho4 = (((quad << 1) | (quad >> 1)) & 3) << 2;  // rho(quad)*4

  // ---- prologue: issue stage of tile 0 first, overlap with qr compute ----
#pragma unroll
  for (int t = 0; t < 2; ++t) {
    gld_lds16(kpB + srcK[t], kv + (wave * 2 + t) * 1024);
    gld_lds16(vpB + srcV[t], kv + 8192 + (wave * 2 + t) * 1024);
  }

  for (int t = lane; t < 16 * 36; t += 64) s_w[t] = 0.f;

  // Q fragments (B-operand; identical lane layout to A for 16x16x32)
  s16x8 qf[2];
#pragma unroll
  for (int ks = 0; ks < 2; ++ks)
    qf[ks] = *(const s16x8*)(qp + (size_t)(wq0 + row16) * HD + ks * 32 + quad * 8);

  // qr^T[bucket][q] = rel_k[bucket] . q  via swapped MFMA (A=RK, B=Q)
  f32x4 a0, a2;
#pragma unroll
  for (int nt = 0; nt < 3; ++nt) {
    f32x4 a = {};
#pragma unroll
    for (int ks = 0; ks < 2; ++ks) {
      s16x8 afr = *(const s16x8*)(RKp + (size_t)(nt * 16 + row16) * HD + ks * 32 + quad * 8);
      a = __builtin_amdgcn_mfma_f32_16x16x32_bf16(afr, qf[ks], a, 0, 0, 0);
    }
    if (nt == 0) a0 = a;
    if (nt == 2) a2 = a;
#pragma unroll
    for (int r = 0; r < 4; ++r) {
      const int bk = nt * 16 + quad * 4 + r;
      if (bk < NBUCKET) qr_w[bk * 17 + row16] = a[r];
    }
  }
  // far biases: bucket 0 / 32 value for this lane's q-row (= row16)
  const float blo = __shfl(a0[0], row16);
  const float bhi = __shfl(a2[0], row16);

  f32x4 oacc[4] = {};
  float rsum = 0.f, plos = 0.f, phis = 0.f;
  int baseg[4];
#pragma unroll
  for (int g = 0; g < 4; ++g) baseg[g] = g * 16 + rho4 - wq0 - row16;

  for (int jt = 0; jt < 16; ++jt) {
    const int j0 = jt * 64;
    if (jt) {  // re-stage K/V tile (single buffer; end-of-iter barrier fenced reads)
#pragma unroll
      for (int t = 0; t < 2; ++t) {
        gld_lds16(kpB + (size_t)j0 * 128 + srcK[t], kv + (wave * 2 + t) * 1024);
        gld_lds16(vpB + (size_t)j0 * 2 + srcV[t], kv + 8192 + (wave * 2 + t) * 1024);
      }
    }
    asm volatile("s_waitcnt vmcnt(0)" ::: "memory");
    __builtin_amdgcn_s_barrier();
    __builtin_amdgcn_sched_barrier(0);

    // ---- S^T = K Q^T : lane holds S^T[j = j0+g*16+rho4+r][q = wq0+row16] ----
    f32x4 sacc[4] = {};
#pragma unroll
    for (int ks = 0; ks < 2; ++ks)
#pragma unroll
      for (int g = 0; g < 4; ++g) {
        const int L = (g * 16 + prow) * 128 + ks * 64 + quad * 16;
        const s16x8 kfr = *(const s16x8*)(kv + (L ^ swzK));
        sacc[g] = __builtin_amdgcn_mfma_f32_16x16x32_bf16(kfr, qf[ks], sacc[g], 0, 0, 0);
      }

    // ---- softmax + bf16 pack (all in registers) ----
    unsigned pk[4][2];
    const bool far_lo = (wq0 >= j0 + 79);
    const bool far_hi = (j0 >= wq0 + 31);
    if (far_lo || far_hi) {
      const float bb = (far_lo ? blo : bhi) * SC2;
      float tacc = 0.f;
#pragma unroll
      for (int g = 0; g < 4; ++g)
#pragma unroll
        for (int rr = 0; rr < 2; ++rr) {
          const float pv0 = __builtin_amdgcn_exp2f(sacc[g][rr * 2] * SC2 + bb);
          const float pv1 = __builtin_amdgcn_exp2f(sacc[g][rr * 2 + 1] * SC2 + bb);
          tacc += pv0 + pv1;
          unsigned c;
          asm("v_cvt_pk_bf16_f32 %0, %1, %2" : "=v"(c) : "v"(pv0), "v"(pv1));
          pk[g][rr] = c;
        }
      rsum += tacc;
      if (far_lo) plos += tacc; else phis += tacc;
    } else {
#pragma unroll
      for (int g = 0; g < 4; ++g)
#pragma unroll
        for (int rr = 0; rr < 2; ++rr) {
          float pv2[2];
#pragma unroll
          for (int e = 0; e < 2; ++e) {
            const int r = rr * 2 + e;
            const int dr = baseg[g] + j0 + r;
            int bk = dr < -16 ? -16 : (dr > 16 ? 16 : dr);
            bk += 16;
            const float bias = qr_w[bk * 17 + row16];
            const float pv = __builtin_amdgcn_exp2f((sacc[g][r] + bias) * SC2);
            pv2[e] = pv;
            rsum += pv;
            if (dr <= -16) plos += pv;
            else if (dr >= 16) phis += pv;
            else atomicAdd(&s_w[row16 * 36 + bk], pv);
          }
          unsigned c;
          asm("v_cvt_pk_bf16_f32 %0, %1, %2" : "=v"(c) : "v"(pv2[0]), "v"(pv2[1]));
          pk[g][rr] = c;
        }
    }

    // ---- P^T B-frag assembly: 4 permlane32_swap, zero LDS ----
    s16x8 pf[2];
#pragma unroll
    for (int ks = 0; ks < 2; ++ks) {
      unsigned x0 = pk[ks * 2][0], y0 = pk[ks * 2 + 1][0];
      unsigned x1 = pk[ks * 2][1], y1 = pk[ks * 2 + 1][1];
      asm("v_permlane32_swap_b32 %0, %1" : "+v"(x0), "+v"(y0));
      asm("v_permlane32_swap_b32 %0, %1" : "+v"(x1), "+v"(y1));
      union { unsigned u[4]; s16x8 v; } pfu;
      pfu.u[0] = x0; pfu.u[1] = x1; pfu.u[2] = y0; pfu.u[3] = y1;
      pf[ks] = pfu.v;
    }

    // ---- O^T += V^T P^T ----
#pragma unroll
    for (int ks = 0; ks < 2; ++ks)
#pragma unroll
      for (int dt = 0; dt < 4; ++dt) {
        const int L = (dt * 16 + row16) * 128 + ks * 64 + quad * 16;
        const s16x8 vfr = *(const s16x8*)(kv + 8192 + (L ^ swzV));
        oacc[dt] = __builtin_amdgcn_mfma_f32_16x16x32_bf16(vfr, pf[ks], oacc[dt], 0, 0, 0);
      }

    asm volatile("s_waitcnt lgkmcnt(0)" ::: "memory");
    __builtin_amdgcn_s_barrier();
    __builtin_amdgcn_sched_barrier(0);
  }

  // quad-reduction of row sums (j space was split across quads)
  float t1 = rsum + __shfl_xor(rsum, 16);
  const float lacc = t1 + __shfl_xor(t1, 32);
  t1 = plos + __shfl_xor(plos, 16);
  const float slo = t1 + __shfl_xor(t1, 32);
  t1 = phis + __shfl_xor(phis, 16);
  const float shi = t1 + __shfl_xor(t1, 32);

  // epilogue: rel_v into kv (loop-final barrier fenced all reads)
  float* rv_sm = (float*)kv;
  for (int t = tid; t < NBUCKET * HD; t += 256) rv_sm[t] = RV[t];
  __syncthreads();

  const int b = bh >> 4, h = bh & 15;
  float rel[4][4] = {};
  for (int bk = 0; bk < NBUCKET; ++bk) {
    float sv = s_w[row16 * 36 + bk];
    if (bk == 0) sv += slo;
    if (bk == 32) sv += shi;
#pragma unroll
    for (int dt = 0; dt < 4; ++dt) {
      const f32x4 rv4 = *(const f32x4*)&rv_sm[bk * HD + dt * 16 + quad * 4];
#pragma unroll
      for (int r = 0; r < 4; ++r) rel[dt][r] += sv * rv4[r];
    }
  }
  const float inv = 1.0f / lacc;
#pragma unroll
  for (int dt = 0; dt < 4; ++dt) {
    ushort4 o;
    o.x = f2bf((oacc[dt][0] + rel[dt][0]) * inv);
    o.y = f2bf((oacc[dt][1] + rel[dt][1]) * inv);
    o.z = f2bf((oacc[dt][2] + rel[dt][2]) * inv);
    o.w = f2bf((oacc[dt][3] + rel[dt][3]) * inv);
    *(ushort4*)&Y[((size_t)(b * LL + wq0 + row16)) * EE + h * HD + dt * 16 + quad * 4] = o;
  }
}

extern "C" void kernel_launch(void* const* d_in, const int* in_sizes, int n_in,
                              void* d_out, int out_size, void* d_ws, size_t ws_size,
                              hipStream_t stream) {
  const float* query = (const float*)d_in[0];
  const float* key_  = (const float*)d_in[1];
  const float* value = (const float*)d_in[2];
  const float* wq = (const float*)d_in[3];
  const float* bq = (const float*)d_in[4];
  const float* wk = (const float*)d_in[5];
  const float* bk = (const float*)d_in[6];
  const float* wv = (const float*)d_in[7];
  const float* bv = (const float*)d_in[8];
  const float* wo = (const float*)d_in[9];
  const float* bo = (const float*)d_in[10];
  const float* rel_k = (const float*)d_in[11];
  const float* rel_v = (const float*)d_in[12];

  char* base = (char*)d_ws;
  size_t off = 0;
  auto alloc = [&](size_t bytes) -> void* {
    void* p = base + off;
    off += (bytes + 255) & ~(size_t)255;
    return p;
  };
  const size_t XE = (size_t)BB * LL * EE;
  u16* wqb   = (u16*)alloc((size_t)EE * EE * 2);
  u16* wkb   = (u16*)alloc((size_t)EE * EE * 2);
  u16* wvb   = (u16*)alloc((size_t)EE * EE * 2);
  u16* wob   = (u16*)alloc((size_t)EE * EE * 2);
  u16* q_ws  = (u16*)alloc(XE * 2);
  u16* k_ws  = (u16*)alloc(XE * 2);
  u16* vt_ws = (u16*)alloc(XE * 2);   // V stored transposed by proj_gemm
  u16* relkp = (u16*)alloc(48 * 64 * 2);
  u16* y_ws  = (u16*)alloc(XE * 2);

  cvt_w<<<4108, 256, 0, stream>>>(wq, wk, wv, wo, rel_k, wqb, wkb, wvb, wob, relkp);

  proj_gemm<<<768, 256, 0, stream>>>(
      query, key_, value, wqb, wkb, wvb, bq, bk, bv, q_ws, k_ws, vt_ws);

  attn_fused<<<1024, 256, 0, stream>>>(q_ws, k_ws, vt_ws, relkp, rel_v, y_ws);

  out_gemm<<<256, 256, 0, stream>>>(y_ws, wob, bo, (float*)d_out);
}

// Round 8
// 225.702 us; speedup vs baseline: 1.2102x; 1.1131x over previous
//
#include <hip/hip_runtime.h>

#define BB 4
#define LL 1024
#define EE 1024
#define HH 16
#define HD 64
#define NBUCKET 33
#define SCALE 0.125f
#define SC2 (0.125f * 1.44269504088896f)

typedef unsigned short u16;
using f32x4 = __attribute__((ext_vector_type(4))) float;
using s16x8 = __attribute__((ext_vector_type(8))) short;

__device__ __forceinline__ u16 f2bf(float f) {
  union { float f; unsigned u; } x; x.f = f;
  unsigned r = (x.u + 0x7fffu + ((x.u >> 16) & 1u)) >> 16;
  return (u16)r;
}

__device__ __forceinline__ void gld_lds16(const void* g, void* s) {
  __builtin_amdgcn_global_load_lds((const __attribute__((address_space(1))) void*)g,
                                   (__attribute__((address_space(3))) void*)s, 16, 0, 0);
}

// ---------------- fp32 -> bf16 converts (single merged launch) ----------------
// [0,12288) q/k/v inputs, [12288,16384) weights, [16384,16396) rel_k pad 48x64.
__global__ __launch_bounds__(256) void cvt_all(
    const float* __restrict__ q, const float* __restrict__ k, const float* __restrict__ v,
    const float* __restrict__ wq, const float* __restrict__ wk, const float* __restrict__ wv,
    const float* __restrict__ wo, const float* __restrict__ rk,
    u16* __restrict__ oq, u16* __restrict__ ok, u16* __restrict__ ov,
    u16* __restrict__ owq, u16* __restrict__ owk, u16* __restrict__ owv,
    u16* __restrict__ owo, u16* __restrict__ ork) {
  const int bid = blockIdx.x;
  const int tid = threadIdx.x;
  if (bid < 12288) {
    const int z = bid >> 12;
    const int i = (bid & 4095) * 256 + tid;
    const float* in = z == 0 ? q : (z == 1 ? k : v);
    u16* out = z == 0 ? oq : (z == 1 ? ok : ov);
    float4 f = ((const float4*)in)[i];
    ushort4 o;
    o.x = f2bf(f.x); o.y = f2bf(f.y); o.z = f2bf(f.z); o.w = f2bf(f.w);
    ((ushort4*)out)[i] = o;
  } else if (bid < 16384) {
    const int z = (bid - 12288) >> 10;
    const int i = ((bid - 12288) & 1023) * 256 + tid;
    const float* in = z == 0 ? wq : (z == 1 ? wk : (z == 2 ? wv : wo));
    u16* out = z == 0 ? owq : (z == 1 ? owk : (z == 2 ? owv : owo));
    float4 f = ((const float4*)in)[i];
    ushort4 o;
    o.x = f2bf(f.x); o.y = f2bf(f.y); o.z = f2bf(f.z); o.w = f2bf(f.w);
    ((ushort4*)out)[i] = o;
  } else {
    const int i = (bid - 16384) * 256 + tid;  // 12*256 = 3072 = 48*64 exact
    ork[i] = (i < 33 * 64) ? f2bf(rk[i]) : (u16)0;
  }
}

// ------- 128x128x64 double-buffered all-DMA bf16 GEMM, C = A * B^T + bias ------
// Round-8: T3-minimal pipeline. stage(kt+1) issued at iter TOP into the alt
// buffer; ONE {lgkmcnt(0); vmcnt(0); barrier} at iter END. The whole compute
// phase covers the DMA latency (round-7 counters: conflicts 0, FETCH ideal,
// but MfmaUtil 13% / 68% idle = exposed vmcnt(0) drain per K-step).
// Both-sides swizzle kept (source col ^= (row&7)*8, frag read ^ (row16&7)*8).
// Correctness: buf[(kt+1)&1] was last ds_read in iter kt-1, fenced by that
// iter's lgkm-drain+barrier; DMA(kt+1) is drained by THIS iter's vmcnt(0).
// MODE 0: bf16 (B,H,L,HD). MODE 1: f32 [M][N]. MODE 2: bf16 (B,H,HD,L).
template <int MODE>
__device__ __forceinline__ void gemm128_dbuf(u16* __restrict__ sm,  // 4 x 8192 u16
                                             const u16* __restrict__ A,
                                             const u16* __restrict__ Bw,
                                             const float* __restrict__ bias,
                                             u16* __restrict__ obf,
                                             float* __restrict__ ofp,
                                             int N, int K, int m0, int n0) {
  const int tid = threadIdx.x;
  const int wave = tid >> 6, lane = tid & 63;
  const int row16 = lane & 15, quad = lane >> 4;
  const int wr = (wave >> 1) * 64, wc = (wave & 1) * 64;
  const int srow = lane >> 3, scol = (lane & 7) * 8;
  const int rsw = (row16 & 7) * 8;  // frag-read XOR (u16 units)

  f32x4 acc[4][4] = {};

  auto stage = [&](int k0, u16* as, u16* bs) {
#pragma unroll
    for (int t = 0; t < 4; ++t) {
      const int chunk = wave * 4 + t;
      const int r = chunk * 8 + srow;
      const int cs = scol ^ ((r & 7) * 8);
      gld_lds16(A + (size_t)(m0 + r) * K + k0 + cs, as + chunk * 512);
      gld_lds16(Bw + (size_t)(n0 + r) * K + k0 + cs, bs + chunk * 512);
    }
  };

  // prologue: stage tile 0, drain, barrier
  stage(0, sm, sm + 8192);
  asm volatile("s_waitcnt vmcnt(0)" ::: "memory");
  __builtin_amdgcn_s_barrier();
  __builtin_amdgcn_sched_barrier(0);

  const int NK = K >> 6;
  for (int kt = 0; kt < NK; ++kt) {
    u16* as = sm + (kt & 1) * 16384;
    u16* bs = as + 8192;
    if (kt + 1 < NK) {
      u16* an = sm + ((kt + 1) & 1) * 16384;
      stage((kt + 1) << 6, an, an + 8192);
    }
#pragma unroll
    for (int ks = 0; ks < 2; ++ks) {
      const int cfs = (ks * 32 + quad * 8) ^ rsw;
      s16x8 af[4], bf[4];
#pragma unroll
      for (int mi = 0; mi < 4; ++mi)
        af[mi] = *(const s16x8*)&as[(wr + mi * 16 + row16) * 64 + cfs];
#pragma unroll
      for (int ni = 0; ni < 4; ++ni)
        bf[ni] = *(const s16x8*)&bs[(wc + ni * 16 + row16) * 64 + cfs];
#pragma unroll
      for (int mi = 0; mi < 4; ++mi)
#pragma unroll
        for (int ni = 0; ni < 4; ++ni)
          acc[mi][ni] = __builtin_amdgcn_mfma_f32_16x16x32_bf16(af[mi], bf[ni], acc[mi][ni], 0, 0, 0);
    }
    // single end-of-iter drain: my ds_reads retired (lgkm) + next tile's DMA
    // (issued at iter top, covered by this compute phase) landed (vmcnt).
    asm volatile("s_waitcnt vmcnt(0) lgkmcnt(0)" ::: "memory");
    __builtin_amdgcn_s_barrier();
    __builtin_amdgcn_sched_barrier(0);
  }

#pragma unroll
  for (int mi = 0; mi < 4; ++mi)
#pragma unroll
    for (int ni = 0; ni < 4; ++ni) {
      const int n = n0 + wc + ni * 16 + row16;
      const float bn = bias[n];
      if (MODE == 2) {
        const int mr0 = m0 + wr + mi * 16 + quad * 4;
        const int b = mr0 >> 10, l = mr0 & 1023;
        const int h = n >> 6, hd = n & 63;
        ushort4 o;
        o.x = f2bf(acc[mi][ni][0] + bn);
        o.y = f2bf(acc[mi][ni][1] + bn);
        o.z = f2bf(acc[mi][ni][2] + bn);
        o.w = f2bf(acc[mi][ni][3] + bn);
        *(ushort4*)&obf[((size_t)((b * HH + h) * HD + hd)) * LL + l] = o;
      } else if (MODE == 0) {
#pragma unroll
        for (int r = 0; r < 4; ++r) {
          const int m = m0 + wr + mi * 16 + quad * 4 + r;
          const float v = acc[mi][ni][r] + bn;
          const int b = m >> 10, l = m & 1023, h = n >> 6, hd = n & 63;
          obf[((size_t)((b * HH + h) * LL + l)) * HD + hd] = f2bf(v);
        }
      } else {
#pragma unroll
        for (int r = 0; r < 4; ++r) {
          const int m = m0 + wr + mi * 16 + quad * 4 + r;
          ofp[(size_t)m * N + n] = acc[mi][ni][r] + bn;
        }
      }
    }
}

__global__ __launch_bounds__(256) void proj_gemm(
    const u16* __restrict__ xq, const u16* __restrict__ xk, const u16* __restrict__ xv,
    const u16* __restrict__ wqb, const u16* __restrict__ wkb, const u16* __restrict__ wvb,
    const float* __restrict__ bq, const float* __restrict__ bk, const float* __restrict__ bv,
    u16* __restrict__ oq, u16* __restrict__ ok, u16* __restrict__ ovt) {
  __shared__ u16 sm[4 * 8192];  // dbuf: {a0,b0,a1,b1}
  // XCD-chunk remap (nwg=768, 768%8==0 -> bijective): blocks sharing an
  // A-panel (n0 fastest) contiguous within one XCD's chunk of 96.
  const int work = (blockIdx.x & 7) * 96 + (blockIdx.x >> 3);
  const int z = work >> 8;
  const int m0 = ((work & 255) >> 3) * 128;
  const int n0 = (work & 7) * 128;
  if (z == 0)
    gemm128_dbuf<0>(sm, xq, wqb, bq, oq, nullptr, EE, EE, m0, n0);
  else if (z == 1)
    gemm128_dbuf<0>(sm, xk, wkb, bk, ok, nullptr, EE, EE, m0, n0);
  else  // V: store directly transposed (B,H,HD,L)
    gemm128_dbuf<2>(sm, xv, wvb, bv, ovt, nullptr, EE, EE, m0, n0);
}

__global__ __launch_bounds__(256) void out_gemm(const u16* __restrict__ Y,
                                                const u16* __restrict__ wob,
                                                const float* __restrict__ bo,
                                                float* __restrict__ out) {
  __shared__ u16 sm[4 * 8192];
  const int work = (blockIdx.x & 7) * 32 + (blockIdx.x >> 3);  // nwg=256, 256%8==0
  const int m0 = (work >> 3) * 128;
  const int n0 = (work & 7) * 128;
  gemm128_dbuf<1>(sm, Y, wob, bo, nullptr, out, EE, EE, m0, n0);
}

// ---------------- fused attention (round-4-proven, verbatim) ----------------
// grid 1024, block 256 (4 waves). Swapped-operand MFMA: QK -> mfma(K,Q), lane
// holds S^T for ONE q-row; P assembled IN REGISTERS (8 cvt_pk + 4 permlane32).
// LDS: kv 16384 (K 8K | V 8K) + qr 9216 + s 9216 = 34816 -> 4 blocks/CU.
// VGPR 80. NOTE round-5 evidence: 2-q-tile merge -> VGPR 156, occupancy
// halved, 61->82 us. Do NOT add per-iteration register state here.
__global__ __launch_bounds__(256) void attn_fused(
    const u16* __restrict__ Q, const u16* __restrict__ Kb, const u16* __restrict__ Vt,
    const u16* __restrict__ RKp, const float* __restrict__ RV, u16* __restrict__ Y) {
  __shared__ __align__(16) float qr_sm[4][576];     // [bucket][q] stride 17
  __shared__ __align__(16) float s_sm[4][16 * 36];  // [q][bucket] stride 36
  __shared__ __align__(16) unsigned char kv[16384]; // K 8K | V 8K; rv_sm epilogue

  const int tid = threadIdx.x;
  const int wave = tid >> 6, lane = tid & 63;
  const int row16 = lane & 15, quad = lane >> 4;
  const int bh = blockIdx.x & 63;          // XCD swizzle
  const int i0 = (blockIdx.x >> 6) * 64;
  const int wq0 = i0 + wave * 16;
  const u16* qp = Q + (size_t)bh * LL * HD;
  const char* kpB = (const char*)(Kb + (size_t)bh * LL * HD);
  const char* vpB = (const char*)(Vt + (size_t)bh * HD * LL);

  float* qr_w = &qr_sm[wave][0];
  float* s_w = &s_sm[wave][0];

  // stage offsets (both-sides swizzle: linear LDS dest, pre-swizzled source)
  int srcK[2], srcV[2];
#pragma unroll
  for (int t = 0; t < 2; ++t) {
    const int cK = (wave * 2 + t) * 64 + lane;
    const int rw = cK >> 3;
    const int cb = ((cK * 16) & 127) ^ ((rw & 7) << 4);
    srcK[t] = rw * 128 + cb;
    srcV[t] = rw * 2048 + cb;
  }
  // rho' row permutation (swap 4-7 <-> 8-11 within each 16) for K reads
  const int q2 = row16 >> 2;
  const int prow = ((((q2 << 1) | (q2 >> 1)) & 3) << 2) + (row16 & 3);
  const int swzK = (prow & 7) << 4;
  const int swzV = (row16 & 7) << 4;
  const int rho4 = (((quad << 1) | (quad >> 1)) & 3) << 2;  // rho(quad)*4

  // ---- prologue: issue stage of tile 0 first, overlap with qr compute ----
#pragma unroll
  for (int t = 0; t < 2; ++t) {
    gld_lds16(kpB + srcK[t], kv + (wave * 2 + t) * 1024);
    gld_lds16(vpB + srcV[t], kv + 8192 + (wave * 2 + t) * 1024);
  }

  for (int t = lane; t < 16 * 36; t += 64) s_w[t] = 0.f;

  // Q fragments (B-operand; identical lane layout to A for 16x16x32)
  s16x8 qf[2];
#pragma unroll
  for (int ks = 0; ks < 2; ++ks)
    qf[ks] = *(const s16x8*)(qp + (size_t)(wq0 + row16) * HD + ks * 32 + quad * 8);

  // qr^T[bucket][q] = rel_k[bucket] . q  via swapped MFMA (A=RK, B=Q)
  f32x4 a0, a2;
#pragma unroll
  for (int nt = 0; nt < 3; ++nt) {
    f32x4 a = {};
#pragma unroll
    for (int ks = 0; ks < 2; ++ks) {
      s16x8 afr = *(const s16x8*)(RKp + (size_t)(nt * 16 + row16) * HD + ks * 32 + quad * 8);
      a = __builtin_amdgcn_mfma_f32_16x16x32_bf16(afr, qf[ks], a, 0, 0, 0);
    }
    if (nt == 0) a0 = a;
    if (nt == 2) a2 = a;
#pragma unroll
    for (int r = 0; r < 4; ++r) {
      const int bk = nt * 16 + quad * 4 + r;
      if (bk < NBUCKET) qr_w[bk * 17 + row16] = a[r];
    }
  }
  // far biases: bucket 0 / 32 value for this lane's q-row (= row16)
  const float blo = __shfl(a0[0], row16);
  const float bhi = __shfl(a2[0], row16);

  f32x4 oacc[4] = {};
  float rsum = 0.f, plos = 0.f, phis = 0.f;
  int baseg[4];
#pragma unroll
  for (int g = 0; g < 4; ++g) baseg[g] = g * 16 + rho4 - wq0 - row16;

  for (int jt = 0; jt < 16; ++jt) {
    const int j0 = jt * 64;
    if (jt) {  // re-stage K/V tile (single buffer; end-of-iter barrier fenced reads)
#pragma unroll
      for (int t = 0; t < 2; ++t) {
        gld_lds16(kpB + (size_t)j0 * 128 + srcK[t], kv + (wave * 2 + t) * 1024);
        gld_lds16(vpB + (size_t)j0 * 2 + srcV[t], kv + 8192 + (wave * 2 + t) * 1024);
      }
    }
    asm volatile("s_waitcnt vmcnt(0)" ::: "memory");
    __builtin_amdgcn_s_barrier();
    __builtin_amdgcn_sched_barrier(0);

    // ---- S^T = K Q^T : lane holds S^T[j = j0+g*16+rho4+r][q = wq0+row16] ----
    f32x4 sacc[4] = {};
#pragma unroll
    for (int ks = 0; ks < 2; ++ks)
#pragma unroll
      for (int g = 0; g < 4; ++g) {
        const int L = (g * 16 + prow) * 128 + ks * 64 + quad * 16;
        const s16x8 kfr = *(const s16x8*)(kv + (L ^ swzK));
        sacc[g] = __builtin_amdgcn_mfma_f32_16x16x32_bf16(kfr, qf[ks], sacc[g], 0, 0, 0);
      }

    // ---- softmax + bf16 pack (all in registers) ----
    unsigned pk[4][2];
    const bool far_lo = (wq0 >= j0 + 79);
    const bool far_hi = (j0 >= wq0 + 31);
    if (far_lo || far_hi) {
      const float bb = (far_lo ? blo : bhi) * SC2;
      float tacc = 0.f;
#pragma unroll
      for (int g = 0; g < 4; ++g)
#pragma unroll
        for (int rr = 0; rr < 2; ++rr) {
          const float pv0 = __builtin_amdgcn_exp2f(sacc[g][rr * 2] * SC2 + bb);
          const float pv1 = __builtin_amdgcn_exp2f(sacc[g][rr * 2 + 1] * SC2 + bb);
          tacc += pv0 + pv1;
          unsigned c;
          asm("v_cvt_pk_bf16_f32 %0, %1, %2" : "=v"(c) : "v"(pv0), "v"(pv1));
          pk[g][rr] = c;
        }
      rsum += tacc;
      if (far_lo) plos += tacc; else phis += tacc;
    } else {
#pragma unroll
      for (int g = 0; g < 4; ++g)
#pragma unroll
        for (int rr = 0; rr < 2; ++rr) {
          float pv2[2];
#pragma unroll
          for (int e = 0; e < 2; ++e) {
            const int r = rr * 2 + e;
            const int dr = baseg[g] + j0 + r;
            int bk = dr < -16 ? -16 : (dr > 16 ? 16 : dr);
            bk += 16;
            const float bias = qr_w[bk * 17 + row16];
            const float pv = __builtin_amdgcn_exp2f((sacc[g][r] + bias) * SC2);
            pv2[e] = pv;
            rsum += pv;
            if (dr <= -16) plos += pv;
            else if (dr >= 16) phis += pv;
            else atomicAdd(&s_w[row16 * 36 + bk], pv);
          }
          unsigned c;
          asm("v_cvt_pk_bf16_f32 %0, %1, %2" : "=v"(c) : "v"(pv2[0]), "v"(pv2[1]));
          pk[g][rr] = c;
        }
    }

    // ---- P^T B-frag assembly: 4 permlane32_swap, zero LDS ----
    s16x8 pf[2];
#pragma unroll
    for (int ks = 0; ks < 2; ++ks) {
      unsigned x0 = pk[ks * 2][0], y0 = pk[ks * 2 + 1][0];
      unsigned x1 = pk[ks * 2][1], y1 = pk[ks * 2 + 1][1];
      asm("v_permlane32_swap_b32 %0, %1" : "+v"(x0), "+v"(y0));
      asm("v_permlane32_swap_b32 %0, %1" : "+v"(x1), "+v"(y1));
      union { unsigned u[4]; s16x8 v; } pfu;
      pfu.u[0] = x0; pfu.u[1] = x1; pfu.u[2] = y0; pfu.u[3] = y1;
      pf[ks] = pfu.v;
    }

    // ---- O^T += V^T P^T ----
#pragma unroll
    for (int ks = 0; ks < 2; ++ks)
#pragma unroll
      for (int dt = 0; dt < 4; ++dt) {
        const int L = (dt * 16 + row16) * 128 + ks * 64 + quad * 16;
        const s16x8 vfr = *(const s16x8*)(kv + 8192 + (L ^ swzV));
        oacc[dt] = __builtin_amdgcn_mfma_f32_16x16x32_bf16(vfr, pf[ks], oacc[dt], 0, 0, 0);
      }

    asm volatile("s_waitcnt lgkmcnt(0)" ::: "memory");
    __builtin_amdgcn_s_barrier();
    __builtin_amdgcn_sched_barrier(0);
  }

  // quad-reduction of row sums (j space was split across quads)
  float t1 = rsum + __shfl_xor(rsum, 16);
  const float lacc = t1 + __shfl_xor(t1, 32);
  t1 = plos + __shfl_xor(plos, 16);
  const float slo = t1 + __shfl_xor(t1, 32);
  t1 = phis + __shfl_xor(phis, 16);
  const float shi = t1 + __shfl_xor(t1, 32);

  // epilogue: rel_v into kv (loop-final barrier fenced all reads)
  float* rv_sm = (float*)kv;
  for (int t = tid; t < NBUCKET * HD; t += 256) rv_sm[t] = RV[t];
  __syncthreads();

  const int b = bh >> 4, h = bh & 15;
  float rel[4][4] = {};
  for (int bk = 0; bk < NBUCKET; ++bk) {
    float sv = s_w[row16 * 36 + bk];
    if (bk == 0) sv += slo;
    if (bk == 32) sv += shi;
#pragma unroll
    for (int dt = 0; dt < 4; ++dt) {
      const f32x4 rv4 = *(const f32x4*)&rv_sm[bk * HD + dt * 16 + quad * 4];
#pragma unroll
      for (int r = 0; r < 4; ++r) rel[dt][r] += sv * rv4[r];
    }
  }
  const float inv = 1.0f / lacc;
#pragma unroll
  for (int dt = 0; dt < 4; ++dt) {
    ushort4 o;
    o.x = f2bf((oacc[dt][0] + rel[dt][0]) * inv);
    o.y = f2bf((oacc[dt][1] + rel[dt][1]) * inv);
    o.z = f2bf((oacc[dt][2] + rel[dt][2]) * inv);
    o.w = f2bf((oacc[dt][3] + rel[dt][3]) * inv);
    *(ushort4*)&Y[((size_t)(b * LL + wq0 + row16)) * EE + h * HD + dt * 16 + quad * 4] = o;
  }
}

extern "C" void kernel_launch(void* const* d_in, const int* in_sizes, int n_in,
                              void* d_out, int out_size, void* d_ws, size_t ws_size,
                              hipStream_t stream) {
  const float* query = (const float*)d_in[0];
  const float* key_  = (const float*)d_in[1];
  const float* value = (const float*)d_in[2];
  const float* wq = (const float*)d_in[3];
  const float* bq = (const float*)d_in[4];
  const float* wk = (const float*)d_in[5];
  const float* bk = (const float*)d_in[6];
  const float* wv = (const float*)d_in[7];
  const float* bv = (const float*)d_in[8];
  const float* wo = (const float*)d_in[9];
  const float* bo = (const float*)d_in[10];
  const float* rel_k = (const float*)d_in[11];
  const float* rel_v = (const float*)d_in[12];

  char* base = (char*)d_ws;
  size_t off = 0;
  auto alloc = [&](size_t bytes) -> void* {
    void* p = base + off;
    off += (bytes + 255) & ~(size_t)255;
    return p;
  };
  const size_t XE = (size_t)BB * LL * EE;
  u16* xq    = (u16*)alloc(XE * 2);
  u16* xk    = (u16*)alloc(XE * 2);
  u16* xv    = (u16*)alloc(XE * 2);
  u16* wqb   = (u16*)alloc((size_t)EE * EE * 2);
  u16* wkb   = (u16*)alloc((size_t)EE * EE * 2);
  u16* wvb   = (u16*)alloc((size_t)EE * EE * 2);
  u16* wob   = (u16*)alloc((size_t)EE * EE * 2);
  u16* q_ws  = (u16*)alloc(XE * 2);
  u16* k_ws  = (u16*)alloc(XE * 2);
  u16* vt_ws = (u16*)alloc(XE * 2);   // V stored transposed by proj_gemm
  u16* relkp = (u16*)alloc(48 * 64 * 2);
  u16* y_ws = xq;   // xq dead after proj_gemm (stream-ordered)

  cvt_all<<<16396, 256, 0, stream>>>(query, key_, value, wq, wk, wv, wo, rel_k,
                                     xq, xk, xv, wqb, wkb, wvb, wob, relkp);

  proj_gemm<<<768, 256, 0, stream>>>(
      xq, xk, xv, wqb, wkb, wvb, bq, bk, bv, q_ws, k_ws, vt_ws);

  attn_fused<<<1024, 256, 0, stream>>>(q_ws, k_ws, vt_ws, relkp, rel_v, y_ws);

  out_gemm<<<256, 256, 0, stream>>>(y_ws, wob, bo, (float*)d_out);
}